// Round 13
// baseline (16.540 us; speedup 1.0000x reference)
//
#include <hip/hip_runtime.h>

typedef __fp16 h2 __attribute__((ext_vector_type(2)));   // matches cvt_pkrtz return
typedef float  v2f __attribute__((ext_vector_type(2)));  // NT-load-compatible float2

// R11 structure verbatim; ONE change: input loads + output stores are
// nontemporal (nt). Theory: harness reset() fills leave ~256MB of dirty
// lines in L3; our cold 48MiB input stream evicts them and pays ~48MiB of
// writeback inside our window (R5: WRITE_SIZE == input size, not output).
// nt marks our streaming lines evict-first so they victimize themselves,
// not the dirty fill data; nt store also skips output RFO.
// (R12 fix: NT builtins need clang ext-vector types, not HIP float2.)
__global__ __launch_bounds__(256, 4) void lut_kernel(const float* __restrict__ in,
                                                     const float* __restrict__ lut,
                                                     float* __restrict__ out,
                                                     int N) {
    __shared__ __align__(16) __fp16 wsm[64][72];  // 144 B rows, b128-friendly pad

    const int t  = threadIdx.x;
    const int nl = t & 63;            // lane = local n
    const int wv = t >> 6;            // wave id 0..3 (parallel b)
    const int n0 = blockIdx.x * 64;
    const int n  = n0 + nl;
    const int b0 = blockIdx.y * 32 + wv;

    // ---- 1) issue lut tile loads FIRST (consumed first; FIFO vmcnt) ----
    const float4* lp = reinterpret_cast<const float4*>(lut + (size_t)n0 * 64);
    const int rr = t >> 2, c4 = t & 3;
    float4 lv[4];
    #pragma unroll
    for (int p = 0; p < 4; ++p)
        lv[p] = lp[rr * 16 + (c4 + p * 4)];       // wave: 4 KB contiguous each

    // ---- 2) issue 4 iterations of input prefetch (NT, behind lut in FIFO) ----
    const v2f* ip = reinterpret_cast<const v2f*>(in) + ((size_t)b0 * N + n) * 3;
    const size_t st  = (size_t)N * 12;            // 4 b-rows in v2f units
    v2f pf[4][3];
    #pragma unroll
    for (int p = 0; p < 4; ++p) {
        const v2f* q = ip + (size_t)p * st;
        pf[p][0] = __builtin_nontemporal_load(q + 0);
        pf[p][1] = __builtin_nontemporal_load(q + 1);
        pf[p][2] = __builtin_nontemporal_load(q + 2);
    }

    // ---- 3) sigma(lut) -> f16 LDS (only waits on the 4 lut loads) ----
    #pragma unroll
    for (int p = 0; p < 4; ++p) {
        const int s = c4 + p * 4;                 // float4 slot 0..15
        h2 a = __builtin_amdgcn_cvt_pkrtz(1.0f / (1.0f + __expf(-lv[p].x)),
                                          1.0f / (1.0f + __expf(-lv[p].y)));
        h2 b = __builtin_amdgcn_cvt_pkrtz(1.0f / (1.0f + __expf(-lv[p].z)),
                                          1.0f / (1.0f + __expf(-lv[p].w)));
        *reinterpret_cast<h2*>(&wsm[rr][s * 4 + 0]) = a;
        *reinterpret_cast<h2*>(&wsm[rr][s * 4 + 2]) = b;
    }
    __syncthreads();

    // ---- this thread's w row: 32 half2 = 32 VGPR (8 x ds_read_b128) ----
    h2 w2[32];
    #pragma unroll
    for (int k = 0; k < 8; ++k) {
        h2 r0 = *reinterpret_cast<const h2*>(&wsm[nl][k * 8 + 0]);
        h2 r1 = *reinterpret_cast<const h2*>(&wsm[nl][k * 8 + 2]);
        h2 r2 = *reinterpret_cast<const h2*>(&wsm[nl][k * 8 + 4]);
        h2 r3 = *reinterpret_cast<const h2*>(&wsm[nl][k * 8 + 6]);
        w2[k * 4 + 0] = r0; w2[k * 4 + 1] = r1;
        w2[k * 4 + 2] = r2; w2[k * 4 + 3] = r3;
    }

    float* op = out + (size_t)b0 * N + n;

    #pragma unroll
    for (int it = 0; it < 8; ++it) {
        const v2f va = pf[it & 3][0], vb = pf[it & 3][1], vc = pf[it & 3][2];
        if (it < 4) {                              // keep 4-deep steady state
            const v2f* q = ip + (size_t)(it + 4) * st;
            pf[it & 3][0] = __builtin_nontemporal_load(q + 0);
            pf[it & 3][1] = __builtin_nontemporal_load(q + 1);
            pf[it & 3][2] = __builtin_nontemporal_load(q + 2);
        }
        const float x0 = va.x, x1 = va.y, x2 = vb.x,
                    x3 = vb.y, x4 = vc.x, x5 = vc.y;
        const float B0 = 1.0f - x0, B1 = 1.0f - x1, B2 = 1.0f - x2,
                    B3 = 1.0f - x3, B4 = 1.0f - x4, B5 = 1.0f - x5;

        // idx i = b0*32+b1*16 + b2*8+b3*4 + b4*2+b5; bit==0 -> x, bit==1 -> 1-x
        const float t01a[4] = {x0 * x1, x0 * B1, B0 * x1, B0 * B1};
        const float t23a[4] = {x2 * x3, x2 * B3, B2 * x3, B2 * B3};
        const h2 q0 = __builtin_amdgcn_cvt_pkrtz(x4 * x5, x4 * B5);
        const h2 q1 = __builtin_amdgcn_cvt_pkrtz(B4 * x5, B4 * B5);

        float acc = 0.0f;
        #pragma unroll
        for (int g = 0; g < 4; ++g) {
            float sg = 0.0f;
            #pragma unroll
            for (int j = 0; j < 4; ++j) {
                float d = __builtin_amdgcn_fdot2(q0, w2[g * 8 + j * 2 + 0], 0.0f, false);
                d       = __builtin_amdgcn_fdot2(q1, w2[g * 8 + j * 2 + 1], d,    false);
                sg = fmaf(t23a[j], d, sg);
            }
            acc = fmaf(t01a[g], sg, acc);
        }
        __builtin_nontemporal_store(acc, op + (size_t)it * 4 * N);
    }
}

extern "C" void kernel_launch(void* const* d_in, const int* in_sizes, int n_in,
                              void* d_out, int out_size, void* d_ws, size_t ws_size,
                              hipStream_t stream) {
    const float* inputs = (const float*)d_in[0];   // [B, N, 6] f32
    const float* lut    = (const float*)d_in[1];   // [N, 64]  f32
    float* out = (float*)d_out;                    // [B, N]   f32

    const int lut_sz = in_sizes[1];                // N*64
    const int N = lut_sz / 64;
    const int B = in_sizes[0] / (6 * N);

    dim3 grid(N / 64, B / 32);
    lut_kernel<<<grid, 256, 0, stream>>>(inputs, lut, out, N);
}

// Round 14
// 15.359 us; speedup vs baseline: 1.0769x; 1.0769x over previous
//
#include <hip/hip_runtime.h>

typedef __fp16 h2 __attribute__((ext_vector_type(2)));   // matches cvt_pkrtz return

// FINAL (R11, best: 15.51us). At the harness-imposed traffic roofline:
// per timed replay the window moves ~111MB of HBM traffic (48MiB cold input
// fetch + ~48MiB L3 dirty-line writeback debt from the harness's 256MB fills
// + output) at the in-situ achievable 6.8 TB/s -> ~16us floor. Nine
// structural variants (f32/f16 math, 16/32 waves, LDS/direct input, NT,
// 2-4 deep pipelines) all land 15.5-17.4us; NT (R13) confirmed the debt
// cannot be dodged from HIP.
// Structure: 64 n-lanes x 4 b-waves, 8 b-iters/thread, grid (N/64, B/32).
// w row = 32 packed f16 pairs (v_dot2_f32_f16); 4-deep input pipeline;
// issue order lut->input->exp so the sigma phase only waits on lut loads.
__global__ __launch_bounds__(256, 4) void lut_kernel(const float* __restrict__ in,
                                                     const float* __restrict__ lut,
                                                     float* __restrict__ out,
                                                     int N) {
    __shared__ __align__(16) __fp16 wsm[64][72];  // 144 B rows, b128-friendly pad

    const int t  = threadIdx.x;
    const int nl = t & 63;            // lane = local n
    const int wv = t >> 6;            // wave id 0..3 (parallel b)
    const int n0 = blockIdx.x * 64;
    const int n  = n0 + nl;
    const int b0 = blockIdx.y * 32 + wv;

    // ---- 1) issue lut tile loads FIRST (consumed first; FIFO vmcnt) ----
    const float4* lp = reinterpret_cast<const float4*>(lut + (size_t)n0 * 64);
    const int rr = t >> 2, c4 = t & 3;
    float4 lv[4];
    #pragma unroll
    for (int p = 0; p < 4; ++p)
        lv[p] = lp[rr * 16 + (c4 + p * 4)];       // wave: 4 KB contiguous each

    // ---- 2) issue 4 iterations of input prefetch (behind lut in FIFO) ----
    const float2* ip = reinterpret_cast<const float2*>(in) + ((size_t)b0 * N + n) * 3;
    const size_t st  = (size_t)N * 12;            // 4 b-rows in float2 units
    float2 pf[4][3];
    #pragma unroll
    for (int p = 0; p < 4; ++p) {
        const float2* q = ip + (size_t)p * st;
        pf[p][0] = q[0]; pf[p][1] = q[1]; pf[p][2] = q[2];
    }

    // ---- 3) sigma(lut) -> f16 LDS (only waits on the 4 lut loads) ----
    #pragma unroll
    for (int p = 0; p < 4; ++p) {
        const int s = c4 + p * 4;                 // float4 slot 0..15
        h2 a = __builtin_amdgcn_cvt_pkrtz(1.0f / (1.0f + __expf(-lv[p].x)),
                                          1.0f / (1.0f + __expf(-lv[p].y)));
        h2 b = __builtin_amdgcn_cvt_pkrtz(1.0f / (1.0f + __expf(-lv[p].z)),
                                          1.0f / (1.0f + __expf(-lv[p].w)));
        *reinterpret_cast<h2*>(&wsm[rr][s * 4 + 0]) = a;
        *reinterpret_cast<h2*>(&wsm[rr][s * 4 + 2]) = b;
    }
    __syncthreads();

    // ---- this thread's w row: 32 half2 = 32 VGPR (8 x ds_read_b128) ----
    h2 w2[32];
    #pragma unroll
    for (int k = 0; k < 8; ++k) {
        h2 r0 = *reinterpret_cast<const h2*>(&wsm[nl][k * 8 + 0]);
        h2 r1 = *reinterpret_cast<const h2*>(&wsm[nl][k * 8 + 2]);
        h2 r2 = *reinterpret_cast<const h2*>(&wsm[nl][k * 8 + 4]);
        h2 r3 = *reinterpret_cast<const h2*>(&wsm[nl][k * 8 + 6]);
        w2[k * 4 + 0] = r0; w2[k * 4 + 1] = r1;
        w2[k * 4 + 2] = r2; w2[k * 4 + 3] = r3;
    }

    float* op = out + (size_t)b0 * N + n;

    #pragma unroll
    for (int it = 0; it < 8; ++it) {
        const float2 va = pf[it & 3][0], vb = pf[it & 3][1], vc = pf[it & 3][2];
        if (it < 4) {                              // keep 4-deep steady state
            const float2* q = ip + (size_t)(it + 4) * st;
            pf[it & 3][0] = q[0]; pf[it & 3][1] = q[1]; pf[it & 3][2] = q[2];
        }
        const float x0 = va.x, x1 = va.y, x2 = vb.x,
                    x3 = vb.y, x4 = vc.x, x5 = vc.y;
        const float B0 = 1.0f - x0, B1 = 1.0f - x1, B2 = 1.0f - x2,
                    B3 = 1.0f - x3, B4 = 1.0f - x4, B5 = 1.0f - x5;

        // idx i = b0*32+b1*16 + b2*8+b3*4 + b4*2+b5; bit==0 -> x, bit==1 -> 1-x
        const float t01a[4] = {x0 * x1, x0 * B1, B0 * x1, B0 * B1};
        const float t23a[4] = {x2 * x3, x2 * B3, B2 * x3, B2 * B3};
        const h2 q0 = __builtin_amdgcn_cvt_pkrtz(x4 * x5, x4 * B5);
        const h2 q1 = __builtin_amdgcn_cvt_pkrtz(B4 * x5, B4 * B5);

        float acc = 0.0f;
        #pragma unroll
        for (int g = 0; g < 4; ++g) {
            float sg = 0.0f;
            #pragma unroll
            for (int j = 0; j < 4; ++j) {
                float d = __builtin_amdgcn_fdot2(q0, w2[g * 8 + j * 2 + 0], 0.0f, false);
                d       = __builtin_amdgcn_fdot2(q1, w2[g * 8 + j * 2 + 1], d,    false);
                sg = fmaf(t23a[j], d, sg);
            }
            acc = fmaf(t01a[g], sg, acc);
        }
        op[(size_t)it * 4 * N] = acc;
    }
}

extern "C" void kernel_launch(void* const* d_in, const int* in_sizes, int n_in,
                              void* d_out, int out_size, void* d_ws, size_t ws_size,
                              hipStream_t stream) {
    const float* inputs = (const float*)d_in[0];   // [B, N, 6] f32
    const float* lut    = (const float*)d_in[1];   // [N, 64]  f32
    float* out = (float*)d_out;                    // [B, N]   f32

    const int lut_sz = in_sizes[1];                // N*64
    const int N = lut_sz / 64;
    const int B = in_sizes[0] / (6 * N);

    dim3 grid(N / 64, B / 32);
    lut_kernel<<<grid, 256, 0, stream>>>(inputs, lut, out, N);
}